// Round 1
// baseline (4440.302 us; speedup 1.0000x reference)
//
#include <hip/hip_runtime.h>

#define T_SEQ 512
#define BATCH 64
#define IN_F  1024
#define HID_F 1024
#define G4    4096

typedef __bf16 bf16x8 __attribute__((ext_vector_type(8)));
typedef float  f32x4  __attribute__((ext_vector_type(4)));
typedef unsigned short u16;
typedef unsigned int   u32;

__device__ __forceinline__ u16 f2bf(float x) {
    u32 u = __builtin_bit_cast(u32, x);
    u = (u + 0x7FFFu + ((u >> 16) & 1u)) >> 16;   // RTNE
    return (u16)u;
}

__device__ __forceinline__ float sigf(float x) {
    return 1.0f / (1.0f + expf(-x));
}

// ---------------- fp32 -> bf16 cast ----------------
__global__ void cast_bf16_k(const float* __restrict__ in, u16* __restrict__ out, long n4) {
    long i = (long)blockIdx.x * blockDim.x + threadIdx.x;
    long stride = (long)gridDim.x * blockDim.x;
    for (; i < n4; i += stride) {
        float4 v = ((const float4*)in)[i];
        ushort4 o = make_ushort4(f2bf(v.x), f2bf(v.y), f2bf(v.z), f2bf(v.w));
        ((ushort4*)out)[i] = o;
    }
}

// ---------------- xg = x @ W_ih^T + (b_ih+b_hh), output transposed [t][4096][64] ----------------
// A = W_ih bf16 [4096][1024] row-major (M = gate rows)
// B = x    bf16 [M_tb][1024] row-major (N = (t,b) rows, used as columns)
// D[g][tb] written to out[(t*4096 + g)*64 + b]
__global__ __launch_bounds__(256) void xg_gemm_k(
    const u16* __restrict__ A, const u16* __restrict__ Bm,
    const float* __restrict__ bih, const float* __restrict__ bhh,
    float* __restrict__ out)
{
    __shared__ __align__(16) u16 As[128][40];   // pad 32->40 to spread banks
    __shared__ __align__(16) u16 Bs[128][40];

    const int tid  = threadIdx.x;
    const int bg   = blockIdx.y * 128;   // gate-row tile
    const int btb  = blockIdx.x * 128;   // (t,b) tile
    const int lane = tid & 63;
    const int wid  = tid >> 6;
    const int wr   = wid >> 1;           // wave row (0..1) -> 64 g rows
    const int wc   = wid & 1;            // wave col (0..1) -> 64 tb cols
    const int lrow = lane & 15;
    const int lq   = lane >> 4;

    f32x4 acc[4][4];
    #pragma unroll
    for (int i = 0; i < 4; ++i)
        #pragma unroll
        for (int j = 0; j < 4; ++j)
            acc[i][j] = (f32x4){0.f, 0.f, 0.f, 0.f};

    for (int k0 = 0; k0 < 1024; k0 += 32) {
        #pragma unroll
        for (int s = 0; s < 2; ++s) {
            int u   = tid + s * 256;        // 512 x 16B units per matrix
            int row = u >> 2;
            int ko  = (u & 3) * 8;
            *(uint4*)&As[row][ko] = *(const uint4*)&A [(size_t)(bg  + row) * 1024 + k0 + ko];
            *(uint4*)&Bs[row][ko] = *(const uint4*)&Bm[(size_t)(btb + row) * 1024 + k0 + ko];
        }
        __syncthreads();

        bf16x8 af[4], bf[4];
        #pragma unroll
        for (int i = 0; i < 4; ++i) {
            af[i] = *(const bf16x8*)&As[wr * 64 + i * 16 + lrow][lq * 8];
            bf[i] = *(const bf16x8*)&Bs[wc * 64 + i * 16 + lrow][lq * 8];
        }
        #pragma unroll
        for (int mi = 0; mi < 4; ++mi)
            #pragma unroll
            for (int ni = 0; ni < 4; ++ni)
                acc[mi][ni] = __builtin_amdgcn_mfma_f32_16x16x32_bf16(af[mi], bf[ni], acc[mi][ni], 0, 0, 0);
        __syncthreads();
    }

    // bias sums for the 16 distinct g rows this lane touches
    float bsum[4][4];
    #pragma unroll
    for (int mi = 0; mi < 4; ++mi)
        #pragma unroll
        for (int r = 0; r < 4; ++r) {
            int g = bg + wr * 64 + mi * 16 + lq * 4 + r;
            bsum[mi][r] = bih[g] + bhh[g];
        }

    #pragma unroll
    for (int mi = 0; mi < 4; ++mi)
        #pragma unroll
        for (int ni = 0; ni < 4; ++ni)
            #pragma unroll
            for (int r = 0; r < 4; ++r) {
                int g  = bg + wr * 64 + mi * 16 + lq * 4 + r;
                int tb = btb + wc * 64 + ni * 16 + lrow;
                int t  = tb >> 6;
                int b  = tb & 63;
                out[((size_t)t * G4 + g) * 64 + b] = acc[mi][ni][r] + bsum[mi][r];
            }
}

// ---------------- one LSTM timestep ----------------
// grid = 256 WGs, block = 256. WG wg owns hidden units j0=wg*4 .. j0+3 (all 4 gates).
// gates[16 rows (gate*4+jj)][64 b] = W_hh_rows @ h_in^T, + xg, fused elementwise.
__global__ __launch_bounds__(256) void lstm_step_k(
    const u16* __restrict__ Whh,     // bf16 [4096][1024]
    const u16* __restrict__ hin,     // bf16 [64][1024]
    u16* __restrict__ hout,          // bf16 [64][1024]
    float* __restrict__ cT,          // f32 [1024][64]  (c[j][b])
    const float* __restrict__ xgT,   // f32 [4096][64] for this t
    float* __restrict__ yt)          // f32 [64][1024] for this t
{
    __shared__ __align__(16) u16 As[16][1032];   // 16 W rows x 1024 k (+8 pad)
    __shared__ float Gs[4][16][17];              // per-wave gate routing

    const int tid = threadIdx.x;
    const int j0  = blockIdx.x * 4;

    // stage the 16 W_hh rows (gate-major: row r -> W row (r>>2)*1024 + j0 + (r&3))
    #pragma unroll
    for (int s = 0; s < 8; ++s) {
        int u    = tid + s * 256;       // 2048 x 16B units
        int row  = u >> 7;              // 128 units per row
        int ko   = (u & 127) * 8;
        int grow = (row >> 2) * 1024 + j0 + (row & 3);
        *(uint4*)&As[row][ko] = *(const uint4*)&Whh[(size_t)grow * 1024 + ko];
    }
    __syncthreads();

    const int lane = tid & 63;
    const int w    = tid >> 6;       // wave -> b quadrant
    const int lrow = lane & 15;
    const int lq   = lane >> 4;

    f32x4 acc[4];
    #pragma unroll
    for (int q = 0; q < 4; ++q) acc[q] = (f32x4){0.f, 0.f, 0.f, 0.f};

    const u16* hrow = hin + (size_t)(w * 16 + lrow) * 1024 + lq * 8;
    const u16* arow = &As[lrow][lq * 8];

    #pragma unroll 2
    for (int s = 0; s < 8; ++s) {
        #pragma unroll
        for (int q = 0; q < 4; ++q) {
            int k0 = (s * 4 + q) * 32;
            bf16x8 a = *(const bf16x8*)(arow + k0);
            bf16x8 b = *(const bf16x8*)(hrow + k0);
            acc[q] = __builtin_amdgcn_mfma_f32_16x16x32_bf16(a, b, acc[q], 0, 0, 0);
        }
    }
    f32x4 g4 = (acc[0] + acc[1]) + (acc[2] + acc[3]);

    // route gates through LDS so each lane gets all 4 gates of one (b, j)
    #pragma unroll
    for (int rg = 0; rg < 4; ++rg)
        Gs[w][lrow][lq * 4 + rg] = g4[rg];   // D row = lq*4+rg, D col(b) = lrow
    __syncthreads();

    const int bb   = lrow;           // b within quadrant
    const int jj   = lq;             // hidden unit within slice
    const int bgl  = w * 16 + bb;    // global b
    const int jidx = j0 + jj;

    float gi = Gs[w][bb][0 + jj];
    float gf = Gs[w][bb][4 + jj];
    float gg = Gs[w][bb][8 + jj];
    float go = Gs[w][bb][12 + jj];

    gi += xgT[(size_t)(0 * 1024 + jidx) * 64 + bgl];
    gf += xgT[(size_t)(1 * 1024 + jidx) * 64 + bgl];
    gg += xgT[(size_t)(2 * 1024 + jidx) * 64 + bgl];
    go += xgT[(size_t)(3 * 1024 + jidx) * 64 + bgl];

    float co = cT[(size_t)jidx * 64 + bgl];
    float cn = sigf(gf) * co + sigf(gi) * tanhf(gg);
    float hn = sigf(go) * tanhf(cn);

    cT[(size_t)jidx * 64 + bgl] = cn;
    hout[(size_t)bgl * 1024 + jidx] = f2bf(hn);
    yt[(size_t)bgl * 1024 + jidx] = hn;
}

extern "C" void kernel_launch(void* const* d_in, const int* in_sizes, int n_in,
                              void* d_out, int out_size, void* d_ws, size_t ws_size,
                              hipStream_t stream) {
    const float* x    = (const float*)d_in[0];
    const float* Wih  = (const float*)d_in[1];
    const float* Whh  = (const float*)d_in[2];
    const float* bih  = (const float*)d_in[3];
    const float* bhh  = (const float*)d_in[4];
    float* y = (float*)d_out;

    char* ws = (char*)d_ws;
    size_t off = 0;
    auto alloc = [&](size_t bytes) { size_t p = off; off += (bytes + 255) & ~(size_t)255; return p; };

    u16* xb    = (u16*)(ws + alloc((size_t)T_SEQ * BATCH * IN_F * 2));  // 64 MB
    u16* wihb  = (u16*)(ws + alloc((size_t)G4 * IN_F * 2));             // 8 MB
    u16* whhb  = (u16*)(ws + alloc((size_t)G4 * HID_F * 2));            // 8 MB
    u16* hbuf0 = (u16*)(ws + alloc((size_t)BATCH * HID_F * 2));
    u16* hbuf1 = (u16*)(ws + alloc((size_t)BATCH * HID_F * 2));
    float* cT  = (float*)(ws + alloc((size_t)HID_F * BATCH * 4));

    // xg ring (transposed): ringT * 4096 * 64 f32 = ringT MB
    size_t slot_bytes = (size_t)G4 * BATCH * 4;
    size_t remain = ws_size > off ? ws_size - off : 0;
    long ringT = (long)(remain / slot_bytes);
    if (ringT > T_SEQ) ringT = T_SEQ;
    ringT &= ~1L;
    if (ringT < 2) ringT = 2;  // assume ws is at least this big
    float* xgT = (float*)(ws + alloc((size_t)ringT * slot_bytes));

    // casts
    cast_bf16_k<<<2048, 256, 0, stream>>>(x,   xb,   (long)T_SEQ * BATCH * IN_F / 4);
    cast_bf16_k<<<512,  256, 0, stream>>>(Wih, wihb, (long)G4 * IN_F / 4);
    cast_bf16_k<<<512,  256, 0, stream>>>(Whh, whhb, (long)G4 * HID_F / 4);

    // zero h (both buffers) and c — they are contiguous
    hipMemsetAsync(hbuf0, 0, (size_t)BATCH * HID_F * 2 * 2 + (size_t)HID_F * BATCH * 4, stream);

    u16* hb[2] = { hbuf0, hbuf1 };

    for (long t0 = 0; t0 < T_SEQ; t0 += ringT) {
        long tc = T_SEQ - t0 < ringT ? T_SEQ - t0 : ringT;
        dim3 ggrid((unsigned)(tc * BATCH / 128), G4 / 128);
        xg_gemm_k<<<ggrid, 256, 0, stream>>>(wihb, xb + (size_t)t0 * BATCH * IN_F, bih, bhh, xgT);
        for (long tt = 0; tt < tc; ++tt) {
            long t = t0 + tt;
            lstm_step_k<<<256, 256, 0, stream>>>(
                whhb, hb[t & 1], hb[(t + 1) & 1], cT,
                xgT + (size_t)tt * G4 * BATCH,
                y + (size_t)t * BATCH * HID_F);
        }
    }
}